// Round 15
// baseline (194.351 us; speedup 1.0000x reference)
//
#include <hip/hip_runtime.h>

typedef __attribute__((ext_vector_type(8))) short short8_t;
typedef __attribute__((ext_vector_type(4))) float f32x4;
typedef __attribute__((ext_vector_type(2))) float f32x2;

#define SEQ  256
#define HID  64
#define FIN  5
#define BB   16
#define TPB  1024
#define BTOT 4096

// ws byte offsets
#define OFF_W0HI 0
#define OFF_W1HI (64*1024)
#define OFF_W2HI (128*1024)
#define OFF_WX   (192*1024)     // 16 KB: layer0 x-chunk A-frags (scaled w_ih0 hi/lo + bias0 hi/lo)
#define OFF_B1   (208*1024)     // 256 f32: gate-interleaved scaled bias1

#define NL2E 1.44269504088896f
#if __has_builtin(__builtin_amdgcn_exp2f)
#define EXP2(v) __builtin_amdgcn_exp2f(v)
#else
#define EXP2(v) __expf((v) * 0.6931471805599453f)
#endif

#define MFMA(A, B, C) __builtin_amdgcn_mfma_f32_16x16x32_bf16((A), (B), (C), 0, 0, 0)

__device__ __forceinline__ float rcp_(float v) { return __builtin_amdgcn_rcpf(v); }
__device__ __forceinline__ unsigned short bf16rtn(float v) {
    unsigned int u = __float_as_uint(v);
    u += 0x7fffu + ((u >> 16) & 1u);
    return (unsigned short)(u >> 16);
}
__device__ __forceinline__ float bf16tof(unsigned short h) {
    return __uint_as_float(((unsigned int)h) << 16);
}
__device__ __forceinline__ float sigf(float v) { return rcp_(1.0f + EXP2(v * -NL2E)); }

// ---------------------------------------------------------------------------
// Prep (identical to R10-R13): weights pre-scaled into exp2 domain (i,f,o rows
// x -log2e, g rows x -2log2e), RTN bf16, pre-fragged for mfma_16x16x32
// (e = ((T*2+ks)*64+lane)*8+i, c = 16T+(lane&15), k = ks*32+(lane>>4)*8+i,
// gate-interleaved cols c=4J+gate). x-chunk A-frag (exact hi/lo of SCALED
// values): k0-9 w_hi (x5 twice), k10-14 w_lo, k15 bias_hi, k16 bias_lo.
// ---------------------------------------------------------------------------
__global__ void prep_kernel(const float* __restrict__ wih0, const float* __restrict__ whh0,
                            const float* __restrict__ bih0, const float* __restrict__ bhh0,
                            const float* __restrict__ wih1, const float* __restrict__ whh1,
                            const float* __restrict__ bih1, const float* __restrict__ bhh1,
                            unsigned char* __restrict__ ws) {
    int idx = blockIdx.x * blockDim.x + threadIdx.x;
    if (idx < 3 * 16384) {
        int mat = idx / 16384, e = idx % 16384;
        int tk   = e >> 9;
        int lane = (e >> 3) & 63;
        int i    = e & 7;
        int c = 16 * (tk >> 1) + (lane & 15);
        int k = (tk & 1) * 32 + (lane >> 4) * 8 + i;
        int gate = c & 3;
        int row = gate * 64 + (c >> 2);         // PyTorch row = gate*64 + J
        float scale = (gate == 2) ? (-2.0f * NL2E) : -NL2E;
        const float* W = (mat == 0) ? whh0 : (mat == 1) ? whh1 : wih1;
        float v = W[row * HID + k] * scale;
        int bhiOff = (mat == 0) ? OFF_W0HI : (mat == 1) ? OFF_W1HI : OFF_W2HI;
        ((unsigned short*)(ws + bhiOff))[e] = bf16rtn(v);
    } else if (idx < 3 * 16384 + 8192) {
        int e = idx - 3 * 16384;
        int w = e >> 9, r2 = e & 511;
        int lane = r2 >> 3, i = r2 & 7;
        int c = 16 * w + (lane & 15);
        int k = (lane >> 4) * 8 + i;
        int gate = c & 3;
        int row = gate * 64 + (c >> 2);
        float scale = (gate == 2) ? (-2.0f * NL2E) : -NL2E;
        unsigned short outv = 0;
        if (k < 15) {
            float v = wih0[row * FIN + (k % 5)] * scale;
            unsigned int vb = __float_as_uint(v);
            if (k < 10) outv = (unsigned short)(vb >> 16);                       // truncated hi
            else        outv = bf16rtn(v - __uint_as_float(vb & 0xffff0000u));   // residual lo
        } else if (k == 15 || k == 16) {
            float bv = (bih0[row] + bhh0[row]) * scale;
            unsigned int vb = __float_as_uint(bv);
            if (k == 15) outv = (unsigned short)(vb >> 16);
            else         outv = bf16rtn(bv - __uint_as_float(vb & 0xffff0000u));
        }
        ((unsigned short*)(ws + OFF_WX))[e] = outv;
    }
    if (idx < 256) {
        int gate = idx & 3;
        int row = gate * 64 + (idx >> 2);
        float scale = (gate == 2) ? (-2.0f * NL2E) : -NL2E;
        ((float*)(ws + OFF_B1))[idx] = (bih1[row] + bhh1[row]) * scale;
    }
}

// ---------------------------------------------------------------------------
// Fused 2-layer LSTM + heads, WAVE-SPECIALIZED (R13 geometry — the measured
// optimum: 16 waves, 4/SIMD, ONE barrier/step):
//   waves 0-7  (L1-group): layer-1 gates for tiles {w, w+8}
//   waves 8-15 (L0-group): layer-0 gates for tiles {w-8, w-8+8}
// R15: MFMA accumulator chains split 4-deep -> 2x 2-deep + packed add
// (halves MFMA latency on the post-barrier critical path).
// ---------------------------------------------------------------------------
__global__ __launch_bounds__(TPB, 4)
void lstm_fused_kernel(const float* __restrict__ x, const unsigned char* __restrict__ ws,
                       const float* __restrict__ ew1, const float* __restrict__ eb1,
                       const float* __restrict__ ew2, const float* __restrict__ eb2,
                       const float* __restrict__ pw1, const float* __restrict__ pb1,
                       const float* __restrict__ pw2, const float* __restrict__ pb2,
                       const float* __restrict__ sw,  const float* __restrict__ sb,
                       float* __restrict__ out) {
    __shared__ __attribute__((aligned(16))) unsigned short VS0[2][2][64][8];
    __shared__ __attribute__((aligned(16))) unsigned short VS1[2][2][64][8];
    __shared__ __attribute__((aligned(16))) unsigned short XF[4][64][8];
    __shared__ float HS[2][16][17];

    const int tid  = threadIdx.x;
    const int lane = tid & 63;
    const int w    = tid >> 6;
    const int b    = lane & 15;
    const int g    = lane >> 4;
    const int b0g  = blockIdx.x * BB;
    const bool isL0 = (w >= 8);
    const int wt   = w & 7;          // tile base: this wave owns tiles wt, wt+8

    for (int i = tid; i < 2 * 2 * 64 * 8; i += TPB) {
        (&VS0[0][0][0][0])[i] = 0; (&VS1[0][0][0][0])[i] = 0;
    }
    for (int i = tid; i < 4 * 64 * 8; i += TPB) (&XF[0][0][0])[i] = 0;

    // ---- weight fragments -> registers (once) ----
    short8_t Fa[2][2], Fb[2][2], FX2[2];
    f32x4 biasA, biasB;
    if (!isL0) {
        #pragma unroll
        for (int s = 0; s < 2; ++s)
            #pragma unroll
            for (int ks = 0; ks < 2; ++ks) {
                const int fo = (((wt + 8 * s) * 2 + ks) * 64 + lane) * 16;
                Fa[s][ks] = *(const short8_t*)(ws + OFF_W1HI + fo);   // whh1
                Fb[s][ks] = *(const short8_t*)(ws + OFF_W2HI + fo);   // wih1
            }
        #pragma unroll
        for (int r = 0; r < 4; ++r) {
            biasA[r] = ((const float*)(ws + OFF_B1))[16 * wt + 4 * g + r];
            biasB[r] = ((const float*)(ws + OFF_B1))[16 * (wt + 8) + 4 * g + r];
        }
    } else {
        #pragma unroll
        for (int s = 0; s < 2; ++s) {
            #pragma unroll
            for (int ks = 0; ks < 2; ++ks) {
                const int fo = (((wt + 8 * s) * 2 + ks) * 64 + lane) * 16;
                Fa[s][ks] = *(const short8_t*)(ws + OFF_W0HI + fo);   // whh0
            }
            FX2[s] = *(const short8_t*)(ws + OFF_WX + ((wt + 8 * s) * 64 + lane) * 16);
        }
        biasA[0] = 0.f; biasA[1] = 0.f; biasA[2] = 0.f; biasA[3] = 0.f;
        biasB = biasA;
    }

    // state write slots: tile wt -> chunk 0, tile wt+8 -> chunk 1 (stb = sta+512)
    const int strow  = ((wt >> 1) & 3) * 16 + b;
    const int stelem = 4 * (wt & 1) + g;
    unsigned short* sta = isL0 ? &VS0[0][0][strow][stelem] : &VS1[0][0][strow][stelem];
    unsigned short* stb = sta + 512;      // buf stride = 1024 elems

    f32x2 cc2 = {0.f, 0.f};
    short8_t xfc;

#define PACK_X(SLOT, RL) {                                                          \
    unsigned int u0 = __float_as_uint(bx0), u1 = __float_as_uint(bx1),              \
                 u2 = __float_as_uint(bx2), u3 = __float_as_uint(bx3),              \
                 u4 = __float_as_uint(bx4);                                         \
    unsigned int h0 = u0 >> 16, h1 = u1 >> 16, h2 = u2 >> 16,                       \
                 h3 = u3 >> 16, h4 = u4 >> 16;                                      \
    unsigned int l0 = bf16rtn(bx0 - __uint_as_float(u0 & 0xffff0000u));             \
    unsigned int l1 = bf16rtn(bx1 - __uint_as_float(u1 & 0xffff0000u));             \
    unsigned int l2 = bf16rtn(bx2 - __uint_as_float(u2 & 0xffff0000u));             \
    unsigned int l3 = bf16rtn(bx3 - __uint_as_float(u3 & 0xffff0000u));             \
    unsigned int l4 = bf16rtn(bx4 - __uint_as_float(u4 & 0xffff0000u));             \
    uint4 cc0, cc1;                                                                 \
    cc0.x = h0 | (h1 << 16); cc0.y = h2 | (h3 << 16);                               \
    cc0.z = h4 | (l0 << 16); cc0.w = l1 | (l2 << 16);                               \
    cc1.x = l3 | (l4 << 16); cc1.y = h0 | (h1 << 16);                               \
    cc1.z = h2 | (h3 << 16); cc1.w = h4 | (0x3F80u << 16);                          \
    *(uint4*)&XF[SLOT][0 * 16 + (RL)][0] = cc0;                                     \
    *(uint4*)&XF[SLOT][1 * 16 + (RL)][0] = cc1;                                     \
}

    // Packed gate math over BOTH tile chains (element 0 = chain-a, 1 = chain-b).
    // Inputs already exp2-domain (i,f,o: -log2e*z ; g: -2log2e*z).
#define GATES2(av0, av1, hv2) {                                                     \
    f32x2 e1 = { EXP2(av0[0]), EXP2(av1[0]) };                                      \
    f32x2 e2 = { EXP2(av0[1]), EXP2(av1[1]) };                                      \
    f32x2 e3 = { EXP2(av0[2]), EXP2(av1[2]) };                                      \
    f32x2 e4 = { EXP2(av0[3]), EXP2(av1[3]) };                                      \
    f32x2 one = { 1.0f, 1.0f };                                                     \
    f32x2 A  = one + e2;                                                            \
    f32x2 B  = (one + e1) * (one + e3);                                             \
    f32x2 num = cc2 * B + (one - e3) * A;                                           \
    f32x2 ab = A * B;                                                               \
    f32x2 rab = { rcp_(ab[0]), rcp_(ab[1]) };                                       \
    cc2 = num * rab;                                                                \
    f32x2 arg5 = cc2 * (-2.0f * NL2E);                                              \
    f32x2 e5 = { EXP2(arg5[0]), EXP2(arg5[1]) };                                    \
    f32x2 d2 = (one + e4) * (one + e5);                                             \
    f32x2 rd = { rcp_(d2[0]), rcp_(d2[1]) };                                        \
    hv2 = (one - e5) * rd;                                                          \
}

    __syncthreads();   // publish zero-init before XF prologue build
    // ---- prologue: build XF slots 0..3 (steps 0..3) + constant k16=1.0 rows ----
    if (tid < 64) {
        int d = tid >> 4, bb = tid & 15;
        const float* xp_ = x + (size_t)(b0g + bb) * (SEQ * FIN) + d * FIN;
        float bx0 = xp_[0], bx1 = xp_[1], bx2 = xp_[2], bx3 = xp_[3], bx4 = xp_[4];
        PACK_X(d, bb)
        XF[d][2 * 16 + bb][0] = 0x3F80;   // k16 = 1.0
    }
    __syncthreads();

    // ---- prologue L0(0): h1_0 -> VS0[1]; seed xfc = XF[1] (for iteration 0) ----
    if (isL0) {
        short8_t xf0 = *(const short8_t*)&XF[0][lane][0];
        f32x4 a0 = MFMA(FX2[0], xf0, biasA);
        f32x4 a1 = MFMA(FX2[1], xf0, biasB);
        f32x2 hv2;
        GATES2(a0, a1, hv2)
        unsigned int pk_;
        asm("v_cvt_pk_bf16_f32 %0, %1, %2" : "=v"(pk_) : "v"(hv2[0]), "v"(hv2[1]));
        sta[1 * 1024] = (unsigned short)pk_;
        stb[1 * 1024] = (unsigned short)(pk_ >> 16);
        xfc = *(const short8_t*)&XF[1][lane][0];
    }

    // ---- main loop: iteration I = 4q+R. L1-group: h2(I); L0-group: h1(I+1).
    // Reads: h2 from VS1[P], h1 from VS0[P^1] (P = I&1); xf carried in regs.
    // Writes: h2(I) -> VS1[P^1]; h1(I+1) -> VS0[P].
    // Builder: L0-wave 8+(I&7) loads x(step I+4) at top, packs to XF[I&3] late;
    // xfc refreshed from XF[(I+2)&3] (published 2 barriers ago -> race-free).
    // MFMA chains: 2-deep halves merged with a packed add (latency cut).
#define ITER(P, R, QEXPR, BEN) {                                                        \
    __syncthreads();                                                                    \
    if (!isL0) {                                                                        \
        short8_t h20 = *(const short8_t*)&VS1[P][0][lane][0];                           \
        short8_t h21 = *(const short8_t*)&VS1[P][1][lane][0];                           \
        short8_t h10 = *(const short8_t*)&VS0[P ^ 1][0][lane][0];                       \
        short8_t h11 = *(const short8_t*)&VS0[P ^ 1][1][lane][0];                       \
        f32x4 z4 = {0.f, 0.f, 0.f, 0.f};                                                \
        __builtin_amdgcn_s_setprio(1);                                                  \
        f32x4 d0 = MFMA(Fa[0][0], h20, biasA);                                          \
        f32x4 d1 = MFMA(Fa[1][0], h20, biasB);                                          \
        f32x4 e0 = MFMA(Fa[0][1], h21, z4);                                             \
        f32x4 e1 = MFMA(Fa[1][1], h21, z4);                                             \
        d0 = MFMA(Fb[0][0], h10, d0); d1 = MFMA(Fb[1][0], h10, d1);                     \
        e0 = MFMA(Fb[0][1], h11, e0); e1 = MFMA(Fb[1][1], h11, e1);                     \
        __builtin_amdgcn_s_setprio(0);                                                  \
        d0 = d0 + e0; d1 = d1 + e1;                                                     \
        f32x2 hv2;                                                                      \
        GATES2(d0, d1, hv2)                                                             \
        unsigned int pk_;                                                               \
        asm("v_cvt_pk_bf16_f32 %0, %1, %2" : "=v"(pk_) : "v"(hv2[0]), "v"(hv2[1]));     \
        sta[(P ^ 1) * 1024] = (unsigned short)pk_;                                      \
        stb[(P ^ 1) * 1024] = (unsigned short)(pk_ >> 16);                              \
    } else {                                                                            \
        const int IDX_ = 4 * (QEXPR) + (R);                                             \
        const bool bw_ = (BEN) && (w == 8 + (IDX_ & 7));                                \
        float bx0, bx1, bx2, bx3, bx4;                                                  \
        if (bw_ && lane < 16) {                                                         \
            const float* xp_ = x + (size_t)(b0g + lane) * (SEQ * FIN)                   \
                                 + (IDX_ + 4) * FIN;                                    \
            bx0 = xp_[0]; bx1 = xp_[1]; bx2 = xp_[2]; bx3 = xp_[3]; bx4 = xp_[4];       \
        }                                                                               \
        short8_t h10 = *(const short8_t*)&VS0[P ^ 1][0][lane][0];                       \
        short8_t h11 = *(const short8_t*)&VS0[P ^ 1][1][lane][0];                       \
        f32x4 z4 = {0.f, 0.f, 0.f, 0.f};                                                \
        __builtin_amdgcn_s_setprio(1);                                                  \
        f32x4 a0 = MFMA(FX2[0], xfc, biasA);                                            \
        f32x4 a1 = MFMA(FX2[1], xfc, biasB);                                            \
        f32x4 b0 = MFMA(Fa[0][0], h10, z4);                                             \
        f32x4 b1 = MFMA(Fa[1][0], h10, z4);                                             \
        a0 = MFMA(Fa[0][1], h11, a0); a1 = MFMA(Fa[1][1], h11, a1);                     \
        __builtin_amdgcn_s_setprio(0);                                                  \
        a0 = a0 + b0; a1 = a1 + b1;                                                     \
        f32x2 hv2;                                                                      \
        GATES2(a0, a1, hv2)                                                             \
        unsigned int pk_;                                                               \
        asm("v_cvt_pk_bf16_f32 %0, %1, %2" : "=v"(pk_) : "v"(hv2[0]), "v"(hv2[1]));     \
        sta[P * 1024] = (unsigned short)pk_;                                            \
        stb[P * 1024] = (unsigned short)(pk_ >> 16);                                    \
        if (bw_ && lane < 16) { PACK_X((R), lane) }                                     \
        xfc = *(const short8_t*)&XF[((R) + 2) & 3][lane][0];                            \
    }                                                                                   \
}

    for (int q = 0; q < 63; ++q) {
        ITER(0, 0, q, 1)
        ITER(1, 1, q, 1)
        ITER(0, 2, q, 1)
        ITER(1, 3, q, 1)
    }
    // tail: iterations 252..255, no builds (L0's step-256 output is unread)
    ITER(0, 0, 63, 0)
    ITER(1, 1, 63, 0)
    ITER(0, 2, 63, 0)
    ITER(1, 3, 63, 0)
#undef ITER
#undef GATES2
#undef PACK_X

    __syncthreads();
    // ---------------- heads: final h2 in VS1 buffer 0 ----------------
    if (tid < 256) {
        int hb_ = tid >> 4, hi_ = tid & 15;
        float ae = eb1[hi_], ap = pb1[hi_];
        for (int j = 0; j < HID; ++j) {
            float h = bf16tof(VS1[0][j >> 5][((j >> 3) & 3) * 16 + hb_][j & 7]);
            ae += h * ew1[hi_ * HID + j];
            ap += h * pw1[hi_ * HID + j];
        }
        HS[0][hb_][hi_] = fmaxf(ae, 0.0f);
        HS[1][hb_][hi_] = fmaxf(ap, 0.0f);
    }
    if (tid >= 256 && tid < 256 + 80) {
        int t2 = tid - 256, sbb = t2 / 5, ss = t2 % 5;
        float a = sb[ss];
        for (int j = 0; j < HID; ++j)
            a += bf16tof(VS1[0][j >> 5][((j >> 3) & 3) * 16 + sbb][j & 7]) * sw[ss * HID + j];
        out[2 * BTOT + (size_t)(b0g + sbb) * 5 + ss] = a;
    }
    __syncthreads();
    if (tid < BB) {
        float eo = eb2[0], po = pb2[0];
        #pragma unroll
        for (int i2 = 0; i2 < 16; ++i2) {
            eo += HS[0][tid][i2] * ew2[i2];
            po += HS[1][tid][i2] * pw2[i2];
        }
        out[b0g + tid]        = sigf(eo);
        out[BTOT + b0g + tid] = sigf(po);
    }
}

extern "C" void kernel_launch(void* const* d_in, const int* in_sizes, int n_in,
                              void* d_out, int out_size, void* d_ws, size_t ws_size,
                              hipStream_t stream) {
    const float* x     = (const float*)d_in[0];
    const float* w_ih0 = (const float*)d_in[1];
    const float* w_hh0 = (const float*)d_in[2];
    const float* b_ih0 = (const float*)d_in[3];
    const float* b_hh0 = (const float*)d_in[4];
    const float* w_ih1 = (const float*)d_in[5];
    const float* w_hh1 = (const float*)d_in[6];
    const float* b_ih1 = (const float*)d_in[7];
    const float* b_hh1 = (const float*)d_in[8];
    const float* ew1 = (const float*)d_in[9];
    const float* eb1 = (const float*)d_in[10];
    const float* ew2 = (const float*)d_in[11];
    const float* eb2 = (const float*)d_in[12];
    const float* pw1 = (const float*)d_in[13];
    const float* pb1 = (const float*)d_in[14];
    const float* pw2 = (const float*)d_in[15];
    const float* pb2 = (const float*)d_in[16];
    const float* sw  = (const float*)d_in[17];
    const float* sb  = (const float*)d_in[18];
    float* out = (float*)d_out;
    unsigned char* ws = (unsigned char*)d_ws;   // ~209 KB used

    hipLaunchKernelGGL(prep_kernel, dim3(224), dim3(256), 0, stream,
                       w_ih0, w_hh0, b_ih0, b_hh0, w_ih1, w_hh1, b_ih1, b_hh1, ws);
    hipLaunchKernelGGL(lstm_fused_kernel, dim3(BTOT / BB), dim3(TPB), 0, stream,
                       x, ws, ew1, eb1, ew2, eb2, pw1, pb1, pw2, pb2, sw, sb, out);
}

// Round 16
// 175.480 us; speedup vs baseline: 1.1075x; 1.1075x over previous
//
#include <hip/hip_runtime.h>

typedef __attribute__((ext_vector_type(8))) short short8_t;
typedef __attribute__((ext_vector_type(4))) float f32x4;
typedef __attribute__((ext_vector_type(2))) float f32x2;

#define SEQ  256
#define HID  64
#define FIN  5
#define BB   16
#define TPB  1024
#define BTOT 4096

// ws byte offsets
#define OFF_W0HI 0
#define OFF_W1HI (64*1024)
#define OFF_W2HI (128*1024)
#define OFF_WX   (192*1024)     // 16 KB: layer0 x-chunk A-frags (scaled w_ih0 hi/lo + bias0 hi/lo)
#define OFF_B1   (208*1024)     // 256 f32: gate-interleaved scaled bias1

#define NL2E 1.44269504088896f
#if __has_builtin(__builtin_amdgcn_exp2f)
#define EXP2(v) __builtin_amdgcn_exp2f(v)
#else
#define EXP2(v) __expf((v) * 0.6931471805599453f)
#endif

#define MFMA(A, B, C) __builtin_amdgcn_mfma_f32_16x16x32_bf16((A), (B), (C), 0, 0, 0)

__device__ __forceinline__ float rcp_(float v) { return __builtin_amdgcn_rcpf(v); }
__device__ __forceinline__ unsigned short bf16rtn(float v) {
    unsigned int u = __float_as_uint(v);
    u += 0x7fffu + ((u >> 16) & 1u);
    return (unsigned short)(u >> 16);
}
__device__ __forceinline__ float bf16tof(unsigned short h) {
    return __uint_as_float(((unsigned int)h) << 16);
}
__device__ __forceinline__ float sigf(float v) { return rcp_(1.0f + EXP2(v * -NL2E)); }

// ---------------------------------------------------------------------------
// Prep (identical to R10-R13): weights pre-scaled into exp2 domain (i,f,o rows
// x -log2e, g rows x -2log2e), RTN bf16, pre-fragged for mfma_16x16x32
// (e = ((T*2+ks)*64+lane)*8+i, c = 16T+(lane&15), k = ks*32+(lane>>4)*8+i,
// gate-interleaved cols c=4J+gate). x-chunk A-frag (exact hi/lo of SCALED
// values): k0-9 w_hi (x5 twice), k10-14 w_lo, k15 bias_hi, k16 bias_lo.
// ---------------------------------------------------------------------------
__global__ void prep_kernel(const float* __restrict__ wih0, const float* __restrict__ whh0,
                            const float* __restrict__ bih0, const float* __restrict__ bhh0,
                            const float* __restrict__ wih1, const float* __restrict__ whh1,
                            const float* __restrict__ bih1, const float* __restrict__ bhh1,
                            unsigned char* __restrict__ ws) {
    int idx = blockIdx.x * blockDim.x + threadIdx.x;
    if (idx < 3 * 16384) {
        int mat = idx / 16384, e = idx % 16384;
        int tk   = e >> 9;
        int lane = (e >> 3) & 63;
        int i    = e & 7;
        int c = 16 * (tk >> 1) + (lane & 15);
        int k = (tk & 1) * 32 + (lane >> 4) * 8 + i;
        int gate = c & 3;
        int row = gate * 64 + (c >> 2);         // PyTorch row = gate*64 + J
        float scale = (gate == 2) ? (-2.0f * NL2E) : -NL2E;
        const float* W = (mat == 0) ? whh0 : (mat == 1) ? whh1 : wih1;
        float v = W[row * HID + k] * scale;
        int bhiOff = (mat == 0) ? OFF_W0HI : (mat == 1) ? OFF_W1HI : OFF_W2HI;
        ((unsigned short*)(ws + bhiOff))[e] = bf16rtn(v);
    } else if (idx < 3 * 16384 + 8192) {
        int e = idx - 3 * 16384;
        int w = e >> 9, r2 = e & 511;
        int lane = r2 >> 3, i = r2 & 7;
        int c = 16 * w + (lane & 15);
        int k = (lane >> 4) * 8 + i;
        int gate = c & 3;
        int row = gate * 64 + (c >> 2);
        float scale = (gate == 2) ? (-2.0f * NL2E) : -NL2E;
        unsigned short outv = 0;
        if (k < 15) {
            float v = wih0[row * FIN + (k % 5)] * scale;
            unsigned int vb = __float_as_uint(v);
            if (k < 10) outv = (unsigned short)(vb >> 16);                       // truncated hi
            else        outv = bf16rtn(v - __uint_as_float(vb & 0xffff0000u));   // residual lo
        } else if (k == 15 || k == 16) {
            float bv = (bih0[row] + bhh0[row]) * scale;
            unsigned int vb = __float_as_uint(bv);
            if (k == 15) outv = (unsigned short)(vb >> 16);
            else         outv = bf16rtn(bv - __uint_as_float(vb & 0xffff0000u));
        }
        ((unsigned short*)(ws + OFF_WX))[e] = outv;
    }
    if (idx < 256) {
        int gate = idx & 3;
        int row = gate * 64 + (idx >> 2);
        float scale = (gate == 2) ? (-2.0f * NL2E) : -NL2E;
        ((float*)(ws + OFF_B1))[idx] = (bih1[row] + bhh1[row]) * scale;
    }
}

// ---------------------------------------------------------------------------
// Fused 2-layer LSTM + heads, WAVE-SPECIALIZED (R11/R12 structure):
//   waves 0-7  (L1-group): layer-1 gates for tiles {w, w+8}
//   waves 8-15 (L0-group): layer-0 gates for tiles {w-8, w-8+8}
// ONE barrier per timestep. R13: GATES vectorized to float2 (both tile
// chains pairwise) so the gate arithmetic emits VOP3P packed-f32 ops —
// halves plain-VALU issue of the pointwise update; bitwise-identical math.
// ---------------------------------------------------------------------------
__global__ __launch_bounds__(TPB, 4)
void lstm_fused_kernel(const float* __restrict__ x, const unsigned char* __restrict__ ws,
                       const float* __restrict__ ew1, const float* __restrict__ eb1,
                       const float* __restrict__ ew2, const float* __restrict__ eb2,
                       const float* __restrict__ pw1, const float* __restrict__ pb1,
                       const float* __restrict__ pw2, const float* __restrict__ pb2,
                       const float* __restrict__ sw,  const float* __restrict__ sb,
                       float* __restrict__ out) {
    __shared__ __attribute__((aligned(16))) unsigned short VS0[2][2][64][8];
    __shared__ __attribute__((aligned(16))) unsigned short VS1[2][2][64][8];
    __shared__ __attribute__((aligned(16))) unsigned short XF[4][64][8];
    __shared__ float HS[2][16][17];

    const int tid  = threadIdx.x;
    const int lane = tid & 63;
    const int w    = tid >> 6;
    const int b    = lane & 15;
    const int g    = lane >> 4;
    const int b0g  = blockIdx.x * BB;
    const bool isL0 = (w >= 8);
    const int wt   = w & 7;          // tile base: this wave owns tiles wt, wt+8

    for (int i = tid; i < 2 * 2 * 64 * 8; i += TPB) {
        (&VS0[0][0][0][0])[i] = 0; (&VS1[0][0][0][0])[i] = 0;
    }
    for (int i = tid; i < 4 * 64 * 8; i += TPB) (&XF[0][0][0])[i] = 0;

    // ---- weight fragments -> registers (once) ----
    short8_t Fa[2][2], Fb[2][2], FX2[2];
    f32x4 biasA, biasB;
    if (!isL0) {
        #pragma unroll
        for (int s = 0; s < 2; ++s)
            #pragma unroll
            for (int ks = 0; ks < 2; ++ks) {
                const int fo = (((wt + 8 * s) * 2 + ks) * 64 + lane) * 16;
                Fa[s][ks] = *(const short8_t*)(ws + OFF_W1HI + fo);   // whh1
                Fb[s][ks] = *(const short8_t*)(ws + OFF_W2HI + fo);   // wih1
            }
        #pragma unroll
        for (int r = 0; r < 4; ++r) {
            biasA[r] = ((const float*)(ws + OFF_B1))[16 * wt + 4 * g + r];
            biasB[r] = ((const float*)(ws + OFF_B1))[16 * (wt + 8) + 4 * g + r];
        }
    } else {
        #pragma unroll
        for (int s = 0; s < 2; ++s) {
            #pragma unroll
            for (int ks = 0; ks < 2; ++ks) {
                const int fo = (((wt + 8 * s) * 2 + ks) * 64 + lane) * 16;
                Fa[s][ks] = *(const short8_t*)(ws + OFF_W0HI + fo);   // whh0
            }
            FX2[s] = *(const short8_t*)(ws + OFF_WX + ((wt + 8 * s) * 64 + lane) * 16);
        }
        biasA[0] = 0.f; biasA[1] = 0.f; biasA[2] = 0.f; biasA[3] = 0.f;
        biasB = biasA;
    }

    // state write slots: tile wt -> chunk 0, tile wt+8 -> chunk 1 (stb = sta+512)
    const int strow  = ((wt >> 1) & 3) * 16 + b;
    const int stelem = 4 * (wt & 1) + g;
    unsigned short* sta = isL0 ? &VS0[0][0][strow][stelem] : &VS1[0][0][strow][stelem];
    unsigned short* stb = sta + 512;      // buf stride = 1024 elems

    f32x2 cc2 = {0.f, 0.f};
    short8_t xfc;

#define PACK_X(SLOT, RL) {                                                          \
    unsigned int u0 = __float_as_uint(bx0), u1 = __float_as_uint(bx1),              \
                 u2 = __float_as_uint(bx2), u3 = __float_as_uint(bx3),              \
                 u4 = __float_as_uint(bx4);                                         \
    unsigned int h0 = u0 >> 16, h1 = u1 >> 16, h2 = u2 >> 16,                       \
                 h3 = u3 >> 16, h4 = u4 >> 16;                                      \
    unsigned int l0 = bf16rtn(bx0 - __uint_as_float(u0 & 0xffff0000u));             \
    unsigned int l1 = bf16rtn(bx1 - __uint_as_float(u1 & 0xffff0000u));             \
    unsigned int l2 = bf16rtn(bx2 - __uint_as_float(u2 & 0xffff0000u));             \
    unsigned int l3 = bf16rtn(bx3 - __uint_as_float(u3 & 0xffff0000u));             \
    unsigned int l4 = bf16rtn(bx4 - __uint_as_float(u4 & 0xffff0000u));             \
    uint4 cc0, cc1;                                                                 \
    cc0.x = h0 | (h1 << 16); cc0.y = h2 | (h3 << 16);                               \
    cc0.z = h4 | (l0 << 16); cc0.w = l1 | (l2 << 16);                               \
    cc1.x = l3 | (l4 << 16); cc1.y = h0 | (h1 << 16);                               \
    cc1.z = h2 | (h3 << 16); cc1.w = h4 | (0x3F80u << 16);                          \
    *(uint4*)&XF[SLOT][0 * 16 + (RL)][0] = cc0;                                     \
    *(uint4*)&XF[SLOT][1 * 16 + (RL)][0] = cc1;                                     \
}

    // Packed gate math over BOTH tile chains (element 0 = chain-a, 1 = chain-b).
    // Inputs already exp2-domain (i,f,o: -log2e*z ; g: -2log2e*z). Per-element
    // arithmetic identical to R12's scalar GATES -> bitwise-identical results.
#define GATES2(av0, av1, hv2) {                                                     \
    f32x2 e1 = { EXP2(av0[0]), EXP2(av1[0]) };                                      \
    f32x2 e2 = { EXP2(av0[1]), EXP2(av1[1]) };                                      \
    f32x2 e3 = { EXP2(av0[2]), EXP2(av1[2]) };                                      \
    f32x2 e4 = { EXP2(av0[3]), EXP2(av1[3]) };                                      \
    f32x2 one = { 1.0f, 1.0f };                                                     \
    f32x2 A  = one + e2;                                                            \
    f32x2 B  = (one + e1) * (one + e3);                                             \
    f32x2 num = cc2 * B + (one - e3) * A;                                           \
    f32x2 ab = A * B;                                                               \
    f32x2 rab = { rcp_(ab[0]), rcp_(ab[1]) };                                       \
    cc2 = num * rab;                                                                \
    f32x2 arg5 = cc2 * (-2.0f * NL2E);                                              \
    f32x2 e5 = { EXP2(arg5[0]), EXP2(arg5[1]) };                                    \
    f32x2 d2 = (one + e4) * (one + e5);                                             \
    f32x2 rd = { rcp_(d2[0]), rcp_(d2[1]) };                                        \
    hv2 = (one - e5) * rd;                                                          \
}

    __syncthreads();   // publish zero-init before XF prologue build
    // ---- prologue: build XF slots 0..3 (steps 0..3) + constant k16=1.0 rows ----
    if (tid < 64) {
        int d = tid >> 4, bb = tid & 15;
        const float* xp_ = x + (size_t)(b0g + bb) * (SEQ * FIN) + d * FIN;
        float bx0 = xp_[0], bx1 = xp_[1], bx2 = xp_[2], bx3 = xp_[3], bx4 = xp_[4];
        PACK_X(d, bb)
        XF[d][2 * 16 + bb][0] = 0x3F80;   // k16 = 1.0
    }
    __syncthreads();

    // ---- prologue L0(0): h1_0 -> VS0[1]; seed xfc = XF[1] (for iteration 0) ----
    if (isL0) {
        short8_t xf0 = *(const short8_t*)&XF[0][lane][0];
        f32x4 a0 = MFMA(FX2[0], xf0, biasA);
        f32x4 a1 = MFMA(FX2[1], xf0, biasB);
        f32x2 hv2;
        GATES2(a0, a1, hv2)
        unsigned int pk_;
        asm("v_cvt_pk_bf16_f32 %0, %1, %2" : "=v"(pk_) : "v"(hv2[0]), "v"(hv2[1]));
        sta[1 * 1024] = (unsigned short)pk_;
        stb[1 * 1024] = (unsigned short)(pk_ >> 16);
        xfc = *(const short8_t*)&XF[1][lane][0];
    }

    // ---- main loop: iteration I = 4q+R. L1-group: h2(I); L0-group: h1(I+1).
    // Reads: h2 from VS1[P], h1 from VS0[P^1] (P = I&1); xf carried in regs.
    // Writes: h2(I) -> VS1[P^1]; h1(I+1) -> VS0[P].
    // Builder: L0-wave 8+(I&7) loads x(step I+4) at top, packs to XF[I&3] late;
    // xfc refreshed from XF[(I+2)&3] (published 2 barriers ago -> race-free).
#define ITER(P, R, QEXPR, BEN) {                                                        \
    __syncthreads();                                                                    \
    if (!isL0) {                                                                        \
        short8_t h20 = *(const short8_t*)&VS1[P][0][lane][0];                           \
        short8_t h21 = *(const short8_t*)&VS1[P][1][lane][0];                           \
        short8_t h10 = *(const short8_t*)&VS0[P ^ 1][0][lane][0];                       \
        short8_t h11 = *(const short8_t*)&VS0[P ^ 1][1][lane][0];                       \
        __builtin_amdgcn_s_setprio(1);                                                  \
        f32x4 d0 = MFMA(Fa[0][0], h20, biasA);                                          \
        f32x4 d1 = MFMA(Fa[1][0], h20, biasB);                                          \
        d0 = MFMA(Fa[0][1], h21, d0); d1 = MFMA(Fa[1][1], h21, d1);                     \
        d0 = MFMA(Fb[0][0], h10, d0); d1 = MFMA(Fb[1][0], h10, d1);                     \
        d0 = MFMA(Fb[0][1], h11, d0); d1 = MFMA(Fb[1][1], h11, d1);                     \
        __builtin_amdgcn_s_setprio(0);                                                  \
        f32x2 hv2;                                                                      \
        GATES2(d0, d1, hv2)                                                             \
        unsigned int pk_;                                                               \
        asm("v_cvt_pk_bf16_f32 %0, %1, %2" : "=v"(pk_) : "v"(hv2[0]), "v"(hv2[1]));     \
        sta[(P ^ 1) * 1024] = (unsigned short)pk_;                                      \
        stb[(P ^ 1) * 1024] = (unsigned short)(pk_ >> 16);                              \
    } else {                                                                            \
        const int IDX_ = 4 * (QEXPR) + (R);                                             \
        const bool bw_ = (BEN) && (w == 8 + (IDX_ & 7));                                \
        float bx0, bx1, bx2, bx3, bx4;                                                  \
        if (bw_ && lane < 16) {                                                         \
            const float* xp_ = x + (size_t)(b0g + lane) * (SEQ * FIN)                   \
                                 + (IDX_ + 4) * FIN;                                    \
            bx0 = xp_[0]; bx1 = xp_[1]; bx2 = xp_[2]; bx3 = xp_[3]; bx4 = xp_[4];       \
        }                                                                               \
        short8_t h10 = *(const short8_t*)&VS0[P ^ 1][0][lane][0];                       \
        short8_t h11 = *(const short8_t*)&VS0[P ^ 1][1][lane][0];                       \
        __builtin_amdgcn_s_setprio(1);                                                  \
        f32x4 a0 = MFMA(FX2[0], xfc, biasA);                                            \
        f32x4 a1 = MFMA(FX2[1], xfc, biasB);                                            \
        a0 = MFMA(Fa[0][0], h10, a0); a1 = MFMA(Fa[1][0], h10, a1);                     \
        a0 = MFMA(Fa[0][1], h11, a0); a1 = MFMA(Fa[1][1], h11, a1);                     \
        __builtin_amdgcn_s_setprio(0);                                                  \
        f32x2 hv2;                                                                      \
        GATES2(a0, a1, hv2)                                                             \
        unsigned int pk_;                                                               \
        asm("v_cvt_pk_bf16_f32 %0, %1, %2" : "=v"(pk_) : "v"(hv2[0]), "v"(hv2[1]));     \
        sta[P * 1024] = (unsigned short)pk_;                                            \
        stb[P * 1024] = (unsigned short)(pk_ >> 16);                                    \
        if (bw_ && lane < 16) { PACK_X((R), lane) }                                     \
        xfc = *(const short8_t*)&XF[((R) + 2) & 3][lane][0];                            \
    }                                                                                   \
}

    for (int q = 0; q < 63; ++q) {
        ITER(0, 0, q, 1)
        ITER(1, 1, q, 1)
        ITER(0, 2, q, 1)
        ITER(1, 3, q, 1)
    }
    // tail: iterations 252..255, no builds (L0's step-256 output is unread)
    ITER(0, 0, 63, 0)
    ITER(1, 1, 63, 0)
    ITER(0, 2, 63, 0)
    ITER(1, 3, 63, 0)
#undef ITER
#undef GATES2
#undef PACK_X

    __syncthreads();
    // ---------------- heads: final h2 in VS1 buffer 0 ----------------
    if (tid < 256) {
        int hb_ = tid >> 4, hi_ = tid & 15;
        float ae = eb1[hi_], ap = pb1[hi_];
        for (int j = 0; j < HID; ++j) {
            float h = bf16tof(VS1[0][j >> 5][((j >> 3) & 3) * 16 + hb_][j & 7]);
            ae += h * ew1[hi_ * HID + j];
            ap += h * pw1[hi_ * HID + j];
        }
        HS[0][hb_][hi_] = fmaxf(ae, 0.0f);
        HS[1][hb_][hi_] = fmaxf(ap, 0.0f);
    }
    if (tid >= 256 && tid < 256 + 80) {
        int t2 = tid - 256, sbb = t2 / 5, ss = t2 % 5;
        float a = sb[ss];
        for (int j = 0; j < HID; ++j)
            a += bf16tof(VS1[0][j >> 5][((j >> 3) & 3) * 16 + sbb][j & 7]) * sw[ss * HID + j];
        out[2 * BTOT + (size_t)(b0g + sbb) * 5 + ss] = a;
    }
    __syncthreads();
    if (tid < BB) {
        float eo = eb2[0], po = pb2[0];
        #pragma unroll
        for (int i2 = 0; i2 < 16; ++i2) {
            eo += HS[0][tid][i2] * ew2[i2];
            po += HS[1][tid][i2] * pw2[i2];
        }
        out[b0g + tid]        = sigf(eo);
        out[BTOT + b0g + tid] = sigf(po);
    }
}

extern "C" void kernel_launch(void* const* d_in, const int* in_sizes, int n_in,
                              void* d_out, int out_size, void* d_ws, size_t ws_size,
                              hipStream_t stream) {
    const float* x     = (const float*)d_in[0];
    const float* w_ih0 = (const float*)d_in[1];
    const float* w_hh0 = (const float*)d_in[2];
    const float* b_ih0 = (const float*)d_in[3];
    const float* b_hh0 = (const float*)d_in[4];
    const float* w_ih1 = (const float*)d_in[5];
    const float* w_hh1 = (const float*)d_in[6];
    const float* b_ih1 = (const float*)d_in[7];
    const float* b_hh1 = (const float*)d_in[8];
    const float* ew1 = (const float*)d_in[9];
    const float* eb1 = (const float*)d_in[10];
    const float* ew2 = (const float*)d_in[11];
    const float* eb2 = (const float*)d_in[12];
    const float* pw1 = (const float*)d_in[13];
    const float* pb1 = (const float*)d_in[14];
    const float* pw2 = (const float*)d_in[15];
    const float* pb2 = (const float*)d_in[16];
    const float* sw  = (const float*)d_in[17];
    const float* sb  = (const float*)d_in[18];
    float* out = (float*)d_out;
    unsigned char* ws = (unsigned char*)d_ws;   // ~209 KB used

    hipLaunchKernelGGL(prep_kernel, dim3(224), dim3(256), 0, stream,
                       w_ih0, w_hh0, b_ih0, b_hh0, w_ih1, w_hh1, b_ih1, b_hh1, ws);
    hipLaunchKernelGGL(lstm_fused_kernel, dim3(BTOT / BB), dim3(TPB), 0, stream,
                       x, ws, ew1, eb1, ew2, eb2, pw1, pb1, pw2, pb2, sw, sb, out);
}